// Round 2
// baseline (645.647 us; speedup 1.0000x reference)
//
#include <hip/hip_runtime.h>

// LinearGaussianSystem via Woodbury:
//   M  = R + H Pinv H^T                (16x16, per batch)
//   Sigma = Pinv - (Pinv H^T) M^-1 (H Pinv)
//   mu = mu0 + (Pinv H^T) M^-1 (y - bias - H mu0)
// Setup kernel precomputes batch-constant factors into d_ws:
//   ws[0..255]    Acm[j][i]  = A[i][j],  A = (H Pinv) H^T   (column-major)
//   ws[256..767]  gcm[s][o]  = G[o][s],  G = H Pinv          (G columns as rows)
//   ws[768..1279] gtc[o][s]  = Gt[s][o], Gt = Pinv H^T       (Gt columns as rows)
//   ws[1280..1791] gtr[s][o] = Gt[s][o]                       (Gt row-major)
//   ws[1792..2815] pvt[c][r] = Pinv[r][c]                     (Pinv transposed)
//   ws[2816..2831] cvec[o]   = bias[o] + (H mu0)[o]
//   ws[2832..2863] mu0[s]

__global__ void lgs_setup(const float* __restrict__ H, const float* __restrict__ bias,
                          const float* __restrict__ mu0, const float* __restrict__ P,
                          float* __restrict__ ws)
{
    __shared__ float aug[32][65];   // [P | I] augmented, padded stride 65
    __shared__ float colk[32];
    __shared__ float Gs[16][32];    // G = H Pinv
    __shared__ float Gts[32][16];   // Gt = Pinv H^T
    const int tid = threadIdx.x;    // 64 threads

    for (int idx = tid; idx < 32 * 64; idx += 64) {
        int r = idx >> 6, c = idx & 63;
        aug[r][c] = (c < 32) ? P[r * 32 + c] : (((c - 32) == r) ? 1.0f : 0.0f);
    }
    __syncthreads();

    // Gauss-Jordan inversion of P (SPD -> no pivoting). Thread tid owns column tid.
    for (int k = 0; k < 32; ++k) {
        if (tid < 32) colk[tid] = aug[tid][k];
        __syncthreads();
        float rk = aug[k][tid] * (1.0f / colk[k]);
        aug[k][tid] = rk;
        for (int r = 0; r < 32; ++r)
            if (r != k) aug[r][tid] -= colk[r] * rk;
        __syncthreads();
    }
    // Pinv[r][c] = aug[r][32+c]

    for (int idx = tid; idx < 16 * 32; idx += 64) {
        int o = idx >> 5, s = idx & 31;
        float acc = 0.f;
        for (int u = 0; u < 32; ++u) acc += H[o * 32 + u] * aug[u][32 + s];
        Gs[o][s] = acc;
    }
    for (int idx = tid; idx < 32 * 16; idx += 64) {
        int s = idx >> 4, o = idx & 15;
        float acc = 0.f;
        for (int u = 0; u < 32; ++u) acc += aug[s][32 + u] * H[o * 32 + u];
        Gts[s][o] = acc;
    }
    __syncthreads();

    for (int idx = tid; idx < 256; idx += 64) {       // Acm[j][i] = A[i][j]
        int j = idx >> 4, i = idx & 15;
        float acc = 0.f;
        for (int s = 0; s < 32; ++s) acc += Gs[i][s] * H[j * 32 + s];
        ws[idx] = acc;
    }
    for (int idx = tid; idx < 512; idx += 64) {       // gcm[s][o] = G[o][s]
        int s = idx >> 4, o = idx & 15;
        ws[256 + idx] = Gs[o][s];
    }
    for (int idx = tid; idx < 512; idx += 64) {       // gtc[o][s] = Gt[s][o]
        int o = idx >> 5, s = idx & 31;
        ws[768 + idx] = Gts[s][o];
    }
    for (int idx = tid; idx < 512; idx += 64) {       // gtr[s][o] = Gt[s][o]
        ws[1280 + idx] = Gts[idx >> 4][idx & 15];
    }
    for (int idx = tid; idx < 1024; idx += 64) {      // pvt[c][r] = Pinv[r][c]
        int c = idx >> 5, r = idx & 31;
        ws[1792 + idx] = aug[r][32 + c];
    }
    if (tid < 16) {
        float acc = bias[tid];
        for (int s = 0; s < 32; ++s) acc += H[tid * 32 + s] * mu0[s];
        ws[2816 + tid] = acc;
    }
    if (tid < 32) ws[2832 + tid] = mu0[tid];
}

// broadcast x from lane ((lane & 0x30) | K) -- lane K of each 16-lane group
#define BCAST16(x, K) __int_as_float(__builtin_amdgcn_ds_swizzle(__float_as_int(x), (((K) << 5) | 0x10)))

template <int K>
__device__ __forceinline__ void gj_step(int t, float (&mcol)[16], float (&w0)[16],
                                        float (&w1)[16], float (&z)[16])
{
    if (t == K) mcol[K] = 1.0f / mcol[K];   // thread K publishes inv-pivot in slot K
    float bc[16];
#pragma unroll
    for (int i = 0; i < 16; ++i) bc[i] = BCAST16(mcol[i], K);
    // bc[K] = 1/pivot, bc[i!=K] = pivot-column entry m[i][K]
    if (t > K) {                            // future pivot columns of M
        float pk = mcol[K] * bc[K];
        mcol[K] = pk;
#pragma unroll
        for (int i = 0; i < 16; ++i)
            if (i != K) mcol[i] -= bc[i] * pk;
    }
    float a0 = w0[K] * bc[K];
    float a1 = w1[K] * bc[K];
    float az = z[K] * bc[K];
    w0[K] = a0; w1[K] = a1; z[K] = az;
#pragma unroll
    for (int i = 0; i < 16; ++i) {
        if (i != K) {
            w0[i] -= bc[i] * a0;
            w1[i] -= bc[i] * a1;
            z[i]  -= bc[i] * az;
        }
    }
}

__global__ __launch_bounds__(256, 4) void lgs_main(
    const float* __restrict__ obs, const float* __restrict__ noise,
    const float* __restrict__ ws,
    float* __restrict__ out_mean, float* __restrict__ out_cov, int B)
{
    const int t = threadIdx.x & 15;                       // column owner within batch group
    const int b = blockIdx.x * 16 + (threadIdx.x >> 4);   // batch element
    if (b >= B) return;

    const float* __restrict__ Acm  = ws;            // [16][16]
    const float* __restrict__ gcm  = ws + 256;      // [32][16]
    const float* __restrict__ gtc  = ws + 768;      // [16][32]
    const float* __restrict__ gtr  = ws + 1280;     // [32][16]
    const float* __restrict__ pvt  = ws + 1792;     // [32][32]
    const float* __restrict__ cvec = ws + 2816;     // [16]
    const float* __restrict__ m0v  = ws + 2832;     // [32]

    float mcol[16], w0[16], w1[16], z[16];

    // M column t = R column t + A column t. R symmetric -> read row t (contiguous).
    const float4* Rr = (const float4*)(noise + (size_t)b * 256 + t * 16);
    const float4* Ar = (const float4*)(Acm + t * 16);
#pragma unroll
    for (int i = 0; i < 4; ++i) {
        float4 r = Rr[i], a = Ar[i];
        mcol[4*i+0] = r.x + a.x; mcol[4*i+1] = r.y + a.y;
        mcol[4*i+2] = r.z + a.z; mcol[4*i+3] = r.w + a.w;
    }
    // RHS columns: w0 = G[:,t], w1 = G[:,t+16], z = y - c (replicated per thread)
    const float4* G0 = (const float4*)(gcm + t * 16);
    const float4* G1 = (const float4*)(gcm + (t + 16) * 16);
    const float4* Yr = (const float4*)(obs + (size_t)b * 16);
    const float4* Cv = (const float4*)cvec;
#pragma unroll
    for (int i = 0; i < 4; ++i) {
        float4 g0 = G0[i];
        w0[4*i+0] = g0.x; w0[4*i+1] = g0.y; w0[4*i+2] = g0.z; w0[4*i+3] = g0.w;
        float4 g1 = G1[i];
        w1[4*i+0] = g1.x; w1[4*i+1] = g1.y; w1[4*i+2] = g1.z; w1[4*i+3] = g1.w;
        float4 y = Yr[i], c = Cv[i];
        z[4*i+0] = y.x - c.x; z[4*i+1] = y.y - c.y;
        z[4*i+2] = y.z - c.z; z[4*i+3] = y.w - c.w;
    }

    // Column-wise Gauss-Jordan: after 16 steps, w0 = W[:,t], w1 = W[:,t+16], z = M^-1 z
    gj_step<0>(t, mcol, w0, w1, z);   gj_step<1>(t, mcol, w0, w1, z);
    gj_step<2>(t, mcol, w0, w1, z);   gj_step<3>(t, mcol, w0, w1, z);
    gj_step<4>(t, mcol, w0, w1, z);   gj_step<5>(t, mcol, w0, w1, z);
    gj_step<6>(t, mcol, w0, w1, z);   gj_step<7>(t, mcol, w0, w1, z);
    gj_step<8>(t, mcol, w0, w1, z);   gj_step<9>(t, mcol, w0, w1, z);
    gj_step<10>(t, mcol, w0, w1, z);  gj_step<11>(t, mcol, w0, w1, z);
    gj_step<12>(t, mcol, w0, w1, z);  gj_step<13>(t, mcol, w0, w1, z);
    gj_step<14>(t, mcol, w0, w1, z);  gj_step<15>(t, mcol, w0, w1, z);

    // posterior mean first (frees z): mu[s] = mu0[s] + sum_o Gt[s][o] * v[o]
    {
        float m0 = m0v[t], m1 = m0v[t + 16];
        const float* g0 = gtr + t * 16;
        const float* g1 = gtr + (t + 16) * 16;
#pragma unroll
        for (int o = 0; o < 16; ++o) {
            m0 += g0[o] * z[o];
            m1 += g1[o] * z[o];
        }
        out_mean[(size_t)b * 32 + t]      = m0;
        out_mean[(size_t)b * 32 + t + 16] = m1;
    }

    // Sigma columns t, t+16 in 4 chunks of 8 rows each (low register pressure):
    // chunk c covers rows s = 8c .. 8c+7:
    //   acc[s] = Pinv[s][t] - sum_o Gt[s][o] * W[o][t]
    // gtc reads are wave-uniform -> scalar loads (SGPR), pvt/stores are per-lane.
    float4* C0 = (float4*)(out_cov + (size_t)b * 1024 + t * 32);
    float4* C1 = C0 + 128;   // row t+16 (Sigma symmetric: column t == row t)
#pragma unroll
    for (int c = 0; c < 4; ++c) {
        float a0[8], a1[8];
        const float4* P0 = (const float4*)(pvt + t * 32 + c * 8);
        const float4* P1 = (const float4*)(pvt + (t + 16) * 32 + c * 8);
        {
            float4 p = P0[0];
            a0[0] = p.x; a0[1] = p.y; a0[2] = p.z; a0[3] = p.w;
            p = P0[1];
            a0[4] = p.x; a0[5] = p.y; a0[6] = p.z; a0[7] = p.w;
            float4 q = P1[0];
            a1[0] = q.x; a1[1] = q.y; a1[2] = q.z; a1[3] = q.w;
            q = P1[1];
            a1[4] = q.x; a1[5] = q.y; a1[6] = q.z; a1[7] = q.w;
        }
#pragma unroll
        for (int o = 0; o < 16; ++o) {
            const float* gv = gtc + o * 32 + c * 8;   // uniform -> SGPR
            float f0 = w0[o], f1 = w1[o];
#pragma unroll
            for (int j = 0; j < 8; ++j) {
                float g = gv[j];
                a0[j] -= g * f0;
                a1[j] -= g * f1;
            }
        }
        C0[c * 2 + 0] = make_float4(a0[0], a0[1], a0[2], a0[3]);
        C0[c * 2 + 1] = make_float4(a0[4], a0[5], a0[6], a0[7]);
        C1[c * 2 + 0] = make_float4(a1[0], a1[1], a1[2], a1[3]);
        C1[c * 2 + 1] = make_float4(a1[4], a1[5], a1[6], a1[7]);
    }
}

extern "C" void kernel_launch(void* const* d_in, const int* in_sizes, int n_in,
                              void* d_out, int out_size, void* d_ws, size_t ws_size,
                              hipStream_t stream)
{
    const float* obs   = (const float*)d_in[0];   // [B,16]
    const float* noise = (const float*)d_in[1];   // [B,16,16]
    const float* H     = (const float*)d_in[2];   // [16,32]
    const float* bias  = (const float*)d_in[3];   // [16]
    const float* mu0   = (const float*)d_in[4];   // [32]
    const float* P     = (const float*)d_in[5];   // [32,32]
    float* ws = (float*)d_ws;

    const int B = in_sizes[0] / 16;
    float* out_mean = (float*)d_out;
    float* out_cov  = out_mean + (size_t)B * 32;

    lgs_setup<<<1, 64, 0, stream>>>(H, bias, mu0, P, ws);
    lgs_main<<<(B + 15) / 16, 256, 0, stream>>>(obs, noise, ws, out_mean, out_cov, B);
}

// Round 3
// 198.587 us; speedup vs baseline: 3.2512x; 3.2512x over previous
//
#include <hip/hip_runtime.h>

// LinearGaussianSystem via Woodbury:
//   M  = R + H Pinv H^T                (16x16, per batch)
//   Sigma = Pinv - (Pinv H^T) M^-1 (H Pinv) = Pinv - G^T W,  W = M^-1 G, G = H Pinv
//   mu = mu0 + G^T M^-1 (y - c) = mu0 + W^T (y - c)   [uses Pinv symmetric => Gt = G^T]
// Setup kernel precomputes batch-constant factors into d_ws (layout as round 1):
//   ws[0..255]     Acm[j][i]  = A[i][j],  A = (H Pinv) H^T   (column-major)
//   ws[256..767]   gcm[s][o]  = G[o][s]                       (G columns as rows)
//   ws[768..1279]  gtc[o][s]  = Gt[s][o], Gt = Pinv H^T       (Gt columns as rows)
//   ws[1280..1791] (unused)
//   ws[1792..2815] pvt[c][r]  = Pinv[r][c]                    (Pinv transposed)
//   ws[2816..2831] cvec[o]    = bias[o] + (H mu0)[o]
//   ws[2832..2863] mu0[s]

__global__ void lgs_setup(const float* __restrict__ H, const float* __restrict__ bias,
                          const float* __restrict__ mu0, const float* __restrict__ P,
                          float* __restrict__ ws)
{
    __shared__ float aug[32][65];   // [P | I] augmented, padded stride 65
    __shared__ float colk[32];
    __shared__ float Gs[16][32];    // G = H Pinv
    __shared__ float Gts[32][16];   // Gt = Pinv H^T
    const int tid = threadIdx.x;    // 64 threads

    for (int idx = tid; idx < 32 * 64; idx += 64) {
        int r = idx >> 6, c = idx & 63;
        aug[r][c] = (c < 32) ? P[r * 32 + c] : (((c - 32) == r) ? 1.0f : 0.0f);
    }
    __syncthreads();

    // Gauss-Jordan inversion of P (SPD -> no pivoting). Thread tid owns column tid.
    for (int k = 0; k < 32; ++k) {
        if (tid < 32) colk[tid] = aug[tid][k];
        __syncthreads();
        float rk = aug[k][tid] * (1.0f / colk[k]);
        aug[k][tid] = rk;
        for (int r = 0; r < 32; ++r)
            if (r != k) aug[r][tid] -= colk[r] * rk;
        __syncthreads();
    }
    // Pinv[r][c] = aug[r][32+c]

    for (int idx = tid; idx < 16 * 32; idx += 64) {
        int o = idx >> 5, s = idx & 31;
        float acc = 0.f;
        for (int u = 0; u < 32; ++u) acc += H[o * 32 + u] * aug[u][32 + s];
        Gs[o][s] = acc;
    }
    for (int idx = tid; idx < 32 * 16; idx += 64) {
        int s = idx >> 4, o = idx & 15;
        float acc = 0.f;
        for (int u = 0; u < 32; ++u) acc += aug[s][32 + u] * H[o * 32 + u];
        Gts[s][o] = acc;
    }
    __syncthreads();

    for (int idx = tid; idx < 256; idx += 64) {       // Acm[j][i] = A[i][j]
        int j = idx >> 4, i = idx & 15;
        float acc = 0.f;
        for (int s = 0; s < 32; ++s) acc += Gs[i][s] * H[j * 32 + s];
        ws[idx] = acc;
    }
    for (int idx = tid; idx < 512; idx += 64) {       // gcm[s][o] = G[o][s]
        int s = idx >> 4, o = idx & 15;
        ws[256 + idx] = Gs[o][s];
    }
    for (int idx = tid; idx < 512; idx += 64) {       // gtc[o][s] = Gt[s][o]
        int o = idx >> 5, s = idx & 31;
        ws[768 + idx] = Gts[s][o];
    }
    for (int idx = tid; idx < 1024; idx += 64) {      // pvt[c][r] = Pinv[r][c]
        int c = idx >> 5, r = idx & 31;
        ws[1792 + idx] = aug[r][32 + c];
    }
    if (tid < 16) {
        float acc = bias[tid];
        for (int s = 0; s < 32; ++s) acc += H[tid * 32 + s] * mu0[s];
        ws[2816 + tid] = acc;
    }
    if (tid < 32) ws[2832 + tid] = mu0[tid];
}

// Broadcast x from lane K of each 32-lane half: BitMode offset = (xor<<10)|(or<<5)|and,
// here and=0, or=K -> src = K (half-local). Two batches per wave, one per half.
#define BCAST32(x, K) __int_as_float(__builtin_amdgcn_ds_swizzle(__float_as_int(x), ((K) << 5)))

// Column-wise GJ solve step. Lane u owns M-column (u&15) in m[] and RHS column u in w[].
// After 16 steps, w = W[:,u] = (M^-1 G)[:,u].
template <int K>
__device__ __forceinline__ void gj32(int u, float (&m)[16], float (&w)[16])
{
    if (u == K) m[K] = 1.0f / m[K];   // column owner publishes inv-pivot in slot K
    float bc[16];
#pragma unroll
    for (int i = 0; i < 16; ++i) bc[i] = BCAST32(m[i], K);
    // bc[K] = 1/pivot, bc[i!=K] = pivot-column entry m[i][K]
    float pk = m[K] * bc[K];          // meaningful for columns u>K; dead elsewhere
#pragma unroll
    for (int i = 0; i < 16; ++i)
        if (i != K) m[i] -= bc[i] * pk;
    m[K] = pk;
    float a = w[K] * bc[K];
#pragma unroll
    for (int i = 0; i < 16; ++i)
        if (i != K) w[i] -= bc[i] * a;
    w[K] = a;
}

__global__ __launch_bounds__(256, 4) void lgs_main(
    const float* __restrict__ obs, const float* __restrict__ noise,
    const float* __restrict__ ws,
    float* __restrict__ out_mean, float* __restrict__ out_cov, int B)
{
    const int u = threadIdx.x & 31;                        // Sigma/W column owner
    const int t = u & 15;                                  // M column owner
    const int b = blockIdx.x * 8 + (threadIdx.x >> 5);     // batch element (8 per block)
    if (b >= B) return;

    const float* __restrict__ Acm  = ws;            // [16][16]
    const float* __restrict__ gcm  = ws + 256;      // [32][16]
    const float* __restrict__ gtc  = ws + 768;      // [16][32]
    const float* __restrict__ pvt  = ws + 1792;     // [32][32]
    const float* __restrict__ cvec = ws + 2816;     // [16]
    const float* __restrict__ m0v  = ws + 2832;     // [32]

    float m[16], w[16];

    // M column t = R column t + A column t (R symmetric -> read row t, contiguous).
    // All 32 lanes init (lanes u>=16 mirror cols 0..15: harmless, never sourced).
    const float4* Rr = (const float4*)(noise + (size_t)b * 256 + t * 16);
    const float4* Ar = (const float4*)(Acm + t * 16);
#pragma unroll
    for (int i = 0; i < 4; ++i) {
        float4 r = Rr[i], a = Ar[i];
        m[4*i+0] = r.x + a.x; m[4*i+1] = r.y + a.y;
        m[4*i+2] = r.z + a.z; m[4*i+3] = r.w + a.w;
    }
    // RHS column u: w = G[:,u]
    const float4* G4 = (const float4*)(gcm + u * 16);
#pragma unroll
    for (int i = 0; i < 4; ++i) {
        float4 g = G4[i];
        w[4*i+0] = g.x; w[4*i+1] = g.y; w[4*i+2] = g.z; w[4*i+3] = g.w;
    }

    gj32<0>(u, m, w);   gj32<1>(u, m, w);   gj32<2>(u, m, w);   gj32<3>(u, m, w);
    gj32<4>(u, m, w);   gj32<5>(u, m, w);   gj32<6>(u, m, w);   gj32<7>(u, m, w);
    gj32<8>(u, m, w);   gj32<9>(u, m, w);   gj32<10>(u, m, w);  gj32<11>(u, m, w);
    gj32<12>(u, m, w);  gj32<13>(u, m, w);  gj32<14>(u, m, w);  gj32<15>(u, m, w);

    // posterior mean, fully local: mu[u] = mu0[u] + sum_o W[o][u] * (y - c)[o]
    {
        float mu = m0v[u];
        const float4* Y4 = (const float4*)(obs + (size_t)b * 16);
        const float4* C4 = (const float4*)cvec;
#pragma unroll
        for (int i = 0; i < 4; ++i) {
            float4 y = Y4[i], c = C4[i];
            mu += w[4*i+0] * (y.x - c.x);
            mu += w[4*i+1] * (y.y - c.y);
            mu += w[4*i+2] * (y.z - c.z);
            mu += w[4*i+3] * (y.w - c.w);
        }
        out_mean[(size_t)b * 32 + u] = mu;   // 32 lanes contiguous
    }

    // Sigma column u (= row u by symmetry), 2 chunks of 16 rows:
    //   acc[s] = Pinv[s][u] - sum_o Gt[s][o] * W[o][u]
    float* Crow = out_cov + (size_t)b * 1024 + u * 32;
#pragma unroll
    for (int c = 0; c < 2; ++c) {
        float acc[16];
        const float4* P4 = (const float4*)(pvt + u * 32 + c * 16);
#pragma unroll
        for (int i = 0; i < 4; ++i) {
            float4 p = P4[i];
            acc[4*i+0] = p.x; acc[4*i+1] = p.y; acc[4*i+2] = p.z; acc[4*i+3] = p.w;
        }
#pragma unroll
        for (int o = 0; o < 16; ++o) {
            const float4* g4 = (const float4*)(gtc + o * 32 + c * 16);
            float f = w[o];
#pragma unroll
            for (int i = 0; i < 4; ++i) {
                float4 g = g4[i];
                acc[4*i+0] -= g.x * f;
                acc[4*i+1] -= g.y * f;
                acc[4*i+2] -= g.z * f;
                acc[4*i+3] -= g.w * f;
            }
        }
        float4* Cs = (float4*)(Crow + c * 16);
#pragma unroll
        for (int i = 0; i < 4; ++i)
            Cs[i] = make_float4(acc[4*i+0], acc[4*i+1], acc[4*i+2], acc[4*i+3]);
    }
}

extern "C" void kernel_launch(void* const* d_in, const int* in_sizes, int n_in,
                              void* d_out, int out_size, void* d_ws, size_t ws_size,
                              hipStream_t stream)
{
    const float* obs   = (const float*)d_in[0];   // [B,16]
    const float* noise = (const float*)d_in[1];   // [B,16,16]
    const float* H     = (const float*)d_in[2];   // [16,32]
    const float* bias  = (const float*)d_in[3];   // [16]
    const float* mu0   = (const float*)d_in[4];   // [32]
    const float* P     = (const float*)d_in[5];   // [32,32]
    float* ws = (float*)d_ws;

    const int B = in_sizes[0] / 16;
    float* out_mean = (float*)d_out;
    float* out_cov  = out_mean + (size_t)B * 32;

    lgs_setup<<<1, 64, 0, stream>>>(H, bias, mu0, P, ws);
    lgs_main<<<(B + 7) / 8, 256, 0, stream>>>(obs, noise, ws, out_mean, out_cov, B);
}